// Round 6
// baseline (336.776 us; speedup 1.0000x reference)
//
#include <hip/hip_runtime.h>
#include <hip/hip_bf16.h>
#include <math.h>

typedef float f4 __attribute__((ext_vector_type(4)));

// Problem constants (seed-0 instance): N=2048, T=512, H=256, E=65536, K=10

// ---------------- Kernel 1: x_agg = mean(x, axis=1) ----------------
// Round-6 structure: 512 blocks x 1024 threads, each block loops over 4
// slabs. Rationale: 2048 concurrent 1MB-apart streams (old layout) spread
// the instantaneous HBM address set over the whole 1.07GB -> row-buffer
// misses (~4.5 TB/s). 512 longer streams with a compact 64KB per-block
// window should raise row-buffer hit rate (fills/copies with compact
// windows measure 6.3-6.4 TB/s).
__global__ __launch_bounds__(1024) void mean_kernel(const float* __restrict__ x,
                                                    float* __restrict__ xagg,
                                                    int T, int H, int N) {
    const int tid = threadIdx.x;
    const int v   = tid & 63;   // float4 index within row (H/4 == 64)
    const int tg  = tid >> 6;   // wave id 0..15

    __shared__ f4 red[1024];

    for (int n = blockIdx.x; n < N; n += gridDim.x) {
        const f4* xr = reinterpret_cast<const f4*>(x + (size_t)n * T * H);
        f4 a0 = {0.f, 0.f, 0.f, 0.f}, a1 = a0, a2 = a0, a3 = a0;
        // rows t = tg + 16*m, m = 0..31, unrolled by 4:
        // block window per iteration = rows 16m .. 16m+63 (64KB contiguous)
        for (int m = 0; m < 32; m += 4) {
            f4 d0 = xr[(tg + 16 * (m + 0)) * 64 + v];
            f4 d1 = xr[(tg + 16 * (m + 1)) * 64 + v];
            f4 d2 = xr[(tg + 16 * (m + 2)) * 64 + v];
            f4 d3 = xr[(tg + 16 * (m + 3)) * 64 + v];
            a0 += d0; a1 += d1; a2 += d2; a3 += d3;
        }
        red[tid] = (a0 + a1) + (a2 + a3);
        __syncthreads();
        if (tid < 64) {
            f4 o = {0.f, 0.f, 0.f, 0.f};
            #pragma unroll
            for (int w = 0; w < 16; ++w) o += red[tid + w * 64];
            o *= (1.0f / (float)T);
            reinterpret_cast<f4*>(xagg + (size_t)n * H)[v] = o;
        }
        __syncthreads();
    }
}

// ---------------- Kernel 2: e = normalize(x_agg @ W^T) ----------------
__global__ __launch_bounds__(128) void proj_norm_kernel(const float* __restrict__ xagg,
                                                        const float* __restrict__ W,
                                                        float* __restrict__ e,
                                                        int H /*256*/) {
    const int n = blockIdx.x;
    const int j = threadIdx.x;  // 0..127

    __shared__ float xs[256];
    xs[j]       = xagg[(size_t)n * H + j];
    xs[j + 128] = xagg[(size_t)n * H + j + 128];
    __syncthreads();

    const float* Wr = W + (size_t)j * H;
    float acc = 0.f;
    #pragma unroll 8
    for (int c = 0; c < 256; ++c) acc = fmaf(Wr[c], xs[c], acc);

    float s = acc * acc;
    #pragma unroll
    for (int off = 32; off; off >>= 1) s += __shfl_xor(s, off);
    __shared__ float nrm[2];
    if ((j & 63) == 0) nrm[j >> 6] = s;
    __syncthreads();
    float tot = nrm[0] + nrm[1];
    float inv = 1.0f / fmaxf(sqrtf(tot), 1e-12f);
    e[(size_t)n * 128 + j] = acc * inv;
}

// ---------------- Kernel 3: sim rows + top-11 extraction + dyn scatter --------
// ROWS=4 rows per block, 256 threads. Phase A: j outer, c4 inner — each
// thread streams its e-row sequentially (full cache-line reuse); eL reads
// are wave-uniform broadcasts. (c4-outer register tile thrashed L1; do not
// reintroduce.) Phase B: wave w extracts top-11 (value desc, index asc),
// drops rank 0 (self).
#define TK_ROWS 4
__global__ __launch_bounds__(256) void simtopk_kernel(const float* __restrict__ e,
                                                      const float* __restrict__ mix,
                                                      float* __restrict__ out,
                                                      int N /*2048*/, int E /*65536*/) {
    __shared__ float eL[TK_ROWS][128];
    __shared__ float simL[TK_ROWS][2048];

    const int i0  = blockIdx.x * TK_ROWS;
    const int tid = threadIdx.x;
    const int M   = E + N * 10;  // 86016

    {
        int r = tid >> 6;
        int c = tid & 63;
        const float* er = e + (size_t)(i0 + r) * 128;
        eL[r][c]      = er[c];
        eL[r][c + 64] = er[c + 64];
    }
    __syncthreads();

    // Phase A: sims for all j, 4 rows at once (j outer, c4 inner)
    for (int j = tid; j < N; j += 256) {
        const f4* ej = reinterpret_cast<const f4*>(e + (size_t)j * 128);
        float acc[TK_ROWS] = {0.f, 0.f, 0.f, 0.f};
        #pragma unroll 4
        for (int c4 = 0; c4 < 32; ++c4) {
            f4 vv = ej[c4];
            #pragma unroll
            for (int r = 0; r < TK_ROWS; ++r) {
                const float* el = &eL[r][c4 * 4];
                acc[r] = fmaf(vv.x, el[0], acc[r]);
                acc[r] = fmaf(vv.y, el[1], acc[r]);
                acc[r] = fmaf(vv.z, el[2], acc[r]);
                acc[r] = fmaf(vv.w, el[3], acc[r]);
            }
        }
        #pragma unroll
        for (int r = 0; r < TK_ROWS; ++r) simL[r][j] = acc[r];
    }
    __syncthreads();

    // Phase B: wave w owns row i0+w
    const int w    = tid >> 6;
    const int lane = tid & 63;
    const int i    = i0 + w;
    const float alpha = 1.0f / (1.0f + expf(-mix[0]));

    float keepv = 0.f;
    int   keepi = 0;
    for (int round = 0; round < 11; ++round) {
        float bv = -3.0f;
        int   bi = N;  // larger than any real index so ties prefer real
        for (int t = 0; t < 32; ++t) {
            int j = t * 64 + lane;
            float v = simL[w][j];
            if (v > bv || (v == bv && j < bi)) { bv = v; bi = j; }
        }
        #pragma unroll
        for (int off = 32; off; off >>= 1) {
            float ov = __shfl_xor(bv, off);
            int   oi = __shfl_xor(bi, off);
            if (ov > bv || (ov == bv && oi < bi)) { bv = ov; bi = oi; }
        }
        if ((bi & 63) == lane && bi < N) simL[w][bi] = -3.0f;
        if (lane == round) { keepv = bv; keepi = bi; }
    }
    if (lane >= 1 && lane <= 10) {
        int kk  = lane - 1;
        int pos = i * 10 + kk;
        out[(size_t)E + pos]         = (float)i;      // row0: src
        out[(size_t)M + E + pos]     = (float)keepi;  // row1: dst
        out[2 * (size_t)M + E + pos] = keepv * alpha; // attr
    }
}

// ---------------- Kernel 4: fixed edges copy/scale ----------------
__global__ __launch_bounds__(256) void fixed_kernel(const int* __restrict__ ei,
                                                    const float* __restrict__ ea,
                                                    const float* __restrict__ mix,
                                                    float* __restrict__ out,
                                                    int E, int M) {
    const int idx = blockIdx.x * blockDim.x + threadIdx.x;
    if (idx < E) {
        float alpha = 1.0f / (1.0f + expf(-mix[0]));
        out[idx]                 = (float)ei[idx];            // row0 fixed src
        out[(size_t)M + idx]     = (float)ei[E + idx];        // row1 fixed dst
        out[2 * (size_t)M + idx] = ea[idx] * (1.0f - alpha);  // fixed attr
    }
}

extern "C" void kernel_launch(void* const* d_in, const int* in_sizes, int n_in,
                              void* d_out, int out_size, void* d_ws, size_t ws_size,
                              hipStream_t stream) {
    const float* x   = (const float*)d_in[0];
    const int*   ei  = (const int*)d_in[1];
    const float* ea  = (const float*)d_in[2];
    const float* W   = (const float*)d_in[3];
    const float* mix = (const float*)d_in[4];

    const int H  = 256;
    const int E  = in_sizes[2];                       // 65536
    const int M  = out_size / 3;                      // 86016
    const int N  = (M - E) / 10;                      // 2048
    const int T  = (int)((size_t)in_sizes[0] / ((size_t)N * H)); // 512

    float* xagg = (float*)d_ws;                       // N*H floats (2 MB)
    float* e    = xagg + (size_t)N * H;               // N*128 floats (1 MB)
    float* out  = (float*)d_out;

    mean_kernel<<<512, 1024, 0, stream>>>(x, xagg, T, H, N);
    proj_norm_kernel<<<N, 128, 0, stream>>>(xagg, W, e, H);
    simtopk_kernel<<<N / TK_ROWS, 256, 0, stream>>>(e, mix, out, N, E);
    fixed_kernel<<<(E + 255) / 256, 256, 0, stream>>>(ei, ea, mix, out, E, M);
}

// Round 7
// 322.002 us; speedup vs baseline: 1.0459x; 1.0459x over previous
//
#include <hip/hip_runtime.h>
#include <hip/hip_bf16.h>
#include <math.h>

typedef float f4 __attribute__((ext_vector_type(4)));

// Problem constants (seed-0 instance): N=2048, T=512, H=256, E=65536, K=10

// ---------------- Kernel 1a: partial sums (copy-shaped) ----------------
// Block bid reduces one contiguous 64KB chunk: n = bid>>3, rows [64c, 64c+64).
// 16 block-wide coalesced sweeps (f4 at k*256+tid), LDS-reduce over the
// 64 rows, write one 1KB partial H-vector. Resident blocks form a compact
// window sweeping memory in dispatch order (the fill/copy regime).
__global__ __launch_bounds__(256) void mean_stageA(const float* __restrict__ x,
                                                   float* __restrict__ part) {
    const int bid  = blockIdx.x;
    const int tid  = threadIdx.x;
    const int lane = tid & 63;

    const f4* xc = reinterpret_cast<const f4*>(x) + (size_t)bid * 4096;
    f4 a0 = {0.f, 0.f, 0.f, 0.f}, a1 = a0, a2 = a0, a3 = a0;
    #pragma unroll
    for (int k = 0; k < 16; k += 4) {
        f4 d0 = xc[(k + 0) * 256 + tid];
        f4 d1 = xc[(k + 1) * 256 + tid];
        f4 d2 = xc[(k + 2) * 256 + tid];
        f4 d3 = xc[(k + 3) * 256 + tid];
        a0 += d0; a1 += d1; a2 += d2; a3 += d3;
    }
    __shared__ f4 red[256];
    red[tid] = (a0 + a1) + (a2 + a3);
    __syncthreads();
    if (tid < 64) {
        f4 o = (red[lane] + red[lane + 64]) + (red[lane + 128] + red[lane + 192]);
        reinterpret_cast<f4*>(part)[(size_t)bid * 64 + lane] = o;
    }
}

// ---------------- Kernel 1b: combine partials -> xagg ----------------
// grid = N blocks x 64 threads; thread j combines the 8 chunk-partials.
__global__ __launch_bounds__(64) void mean_stageB(const float* __restrict__ part,
                                                  float* __restrict__ xagg,
                                                  int T) {
    const int n = blockIdx.x;
    const int j = threadIdx.x;  // 0..63 f4 index over H
    const f4* p = reinterpret_cast<const f4*>(part) + (size_t)n * 8 * 64;
    f4 o = {0.f, 0.f, 0.f, 0.f};
    #pragma unroll
    for (int c = 0; c < 8; ++c) o += p[c * 64 + j];
    o *= (1.0f / (float)T);
    reinterpret_cast<f4*>(xagg)[(size_t)n * 64 + j] = o;
}

// ---------------- Kernel 2: e = normalize(x_agg @ W^T) ----------------
__global__ __launch_bounds__(128) void proj_norm_kernel(const float* __restrict__ xagg,
                                                        const float* __restrict__ W,
                                                        float* __restrict__ e,
                                                        int H /*256*/) {
    const int n = blockIdx.x;
    const int j = threadIdx.x;  // 0..127

    __shared__ float xs[256];
    xs[j]       = xagg[(size_t)n * H + j];
    xs[j + 128] = xagg[(size_t)n * H + j + 128];
    __syncthreads();

    const float* Wr = W + (size_t)j * H;
    float acc = 0.f;
    #pragma unroll 8
    for (int c = 0; c < 256; ++c) acc = fmaf(Wr[c], xs[c], acc);

    float s = acc * acc;
    #pragma unroll
    for (int off = 32; off; off >>= 1) s += __shfl_xor(s, off);
    __shared__ float nrm[2];
    if ((j & 63) == 0) nrm[j >> 6] = s;
    __syncthreads();
    float tot = nrm[0] + nrm[1];
    float inv = 1.0f / fmaxf(sqrtf(tot), 1e-12f);
    e[(size_t)n * 128 + j] = acc * inv;
}

// ---------------- Kernel 3: sim rows + top-11 extraction + dyn scatter --------
// ROWS=4 rows per block, 256 threads. Phase A: j outer, c4 inner — each
// thread streams its e-row sequentially (full cache-line reuse); eL reads
// are wave-uniform broadcasts. (c4-outer register tile thrashed L1; do not
// reintroduce.) Phase B: wave w extracts top-11 (value desc, index asc),
// drops rank 0 (self).
#define TK_ROWS 4
__global__ __launch_bounds__(256) void simtopk_kernel(const float* __restrict__ e,
                                                      const float* __restrict__ mix,
                                                      float* __restrict__ out,
                                                      int N /*2048*/, int E /*65536*/) {
    __shared__ float eL[TK_ROWS][128];
    __shared__ float simL[TK_ROWS][2048];

    const int i0  = blockIdx.x * TK_ROWS;
    const int tid = threadIdx.x;
    const int M   = E + N * 10;  // 86016

    {
        int r = tid >> 6;
        int c = tid & 63;
        const float* er = e + (size_t)(i0 + r) * 128;
        eL[r][c]      = er[c];
        eL[r][c + 64] = er[c + 64];
    }
    __syncthreads();

    // Phase A: sims for all j, 4 rows at once (j outer, c4 inner)
    for (int j = tid; j < N; j += 256) {
        const f4* ej = reinterpret_cast<const f4*>(e + (size_t)j * 128);
        float acc[TK_ROWS] = {0.f, 0.f, 0.f, 0.f};
        #pragma unroll 4
        for (int c4 = 0; c4 < 32; ++c4) {
            f4 vv = ej[c4];
            #pragma unroll
            for (int r = 0; r < TK_ROWS; ++r) {
                const float* el = &eL[r][c4 * 4];
                acc[r] = fmaf(vv.x, el[0], acc[r]);
                acc[r] = fmaf(vv.y, el[1], acc[r]);
                acc[r] = fmaf(vv.z, el[2], acc[r]);
                acc[r] = fmaf(vv.w, el[3], acc[r]);
            }
        }
        #pragma unroll
        for (int r = 0; r < TK_ROWS; ++r) simL[r][j] = acc[r];
    }
    __syncthreads();

    // Phase B: wave w owns row i0+w
    const int w    = tid >> 6;
    const int lane = tid & 63;
    const int i    = i0 + w;
    const float alpha = 1.0f / (1.0f + expf(-mix[0]));

    float keepv = 0.f;
    int   keepi = 0;
    for (int round = 0; round < 11; ++round) {
        float bv = -3.0f;
        int   bi = N;  // larger than any real index so ties prefer real
        for (int t = 0; t < 32; ++t) {
            int j = t * 64 + lane;
            float v = simL[w][j];
            if (v > bv || (v == bv && j < bi)) { bv = v; bi = j; }
        }
        #pragma unroll
        for (int off = 32; off; off >>= 1) {
            float ov = __shfl_xor(bv, off);
            int   oi = __shfl_xor(bi, off);
            if (ov > bv || (ov == bv && oi < bi)) { bv = ov; bi = oi; }
        }
        if ((bi & 63) == lane && bi < N) simL[w][bi] = -3.0f;
        if (lane == round) { keepv = bv; keepi = bi; }
    }
    if (lane >= 1 && lane <= 10) {
        int kk  = lane - 1;
        int pos = i * 10 + kk;
        out[(size_t)E + pos]         = (float)i;      // row0: src
        out[(size_t)M + E + pos]     = (float)keepi;  // row1: dst
        out[2 * (size_t)M + E + pos] = keepv * alpha; // attr
    }
}

// ---------------- Kernel 4: fixed edges copy/scale ----------------
__global__ __launch_bounds__(256) void fixed_kernel(const int* __restrict__ ei,
                                                    const float* __restrict__ ea,
                                                    const float* __restrict__ mix,
                                                    float* __restrict__ out,
                                                    int E, int M) {
    const int idx = blockIdx.x * blockDim.x + threadIdx.x;
    if (idx < E) {
        float alpha = 1.0f / (1.0f + expf(-mix[0]));
        out[idx]                 = (float)ei[idx];            // row0 fixed src
        out[(size_t)M + idx]     = (float)ei[E + idx];        // row1 fixed dst
        out[2 * (size_t)M + idx] = ea[idx] * (1.0f - alpha);  // fixed attr
    }
}

extern "C" void kernel_launch(void* const* d_in, const int* in_sizes, int n_in,
                              void* d_out, int out_size, void* d_ws, size_t ws_size,
                              hipStream_t stream) {
    const float* x   = (const float*)d_in[0];
    const int*   ei  = (const int*)d_in[1];
    const float* ea  = (const float*)d_in[2];
    const float* W   = (const float*)d_in[3];
    const float* mix = (const float*)d_in[4];

    const int H  = 256;
    const int E  = in_sizes[2];                       // 65536
    const int M  = out_size / 3;                      // 86016
    const int N  = (M - E) / 10;                      // 2048
    const int T  = (int)((size_t)in_sizes[0] / ((size_t)N * H)); // 512

    float* xagg = (float*)d_ws;                       // N*H floats (2 MB)
    float* e    = xagg + (size_t)N * H;               // N*128 floats (1 MB)
    float* part = e + (size_t)N * 128;                // N*8*H floats (16 MB)
    float* out  = (float*)d_out;

    const int nchunks = N * 8;                        // 16384 (64KB each)
    mean_stageA<<<nchunks, 256, 0, stream>>>(x, part);
    mean_stageB<<<N, 64, 0, stream>>>(part, xagg, T);
    proj_norm_kernel<<<N, 128, 0, stream>>>(xagg, W, e, H);
    simtopk_kernel<<<N / TK_ROWS, 256, 0, stream>>>(e, mix, out, N, E);
    fixed_kernel<<<(E + 255) / 256, 256, 0, stream>>>(ei, ea, mix, out, E, M);
}

// Round 8
// 286.595 us; speedup vs baseline: 1.1751x; 1.1235x over previous
//
#include <hip/hip_runtime.h>
#include <hip/hip_bf16.h>
#include <math.h>

typedef float f4 __attribute__((ext_vector_type(4)));

// Problem constants (seed-0 instance): N=2048, T=512, H=256, E=65536, K=10

// ---------------- Kernel 1: x_agg = mean(x, axis=1) ----------------
// R5 structure (block-per-row, wave-interleaved rows, 4-acc ILP) — best of
// R2/R5/R6(512x1024)/R7(two-stage). Stream-count sweep {512,2048,16384} all
// ~4.2-4.3 TB/s => not a locality problem; testing L2/L3-allocation bypass.
// SINGLE VARIABLE vs R5: nontemporal loads (stream >> L3, zero reuse).
__global__ __launch_bounds__(256) void mean_kernel(const float* __restrict__ x,
                                                   float* __restrict__ xagg,
                                                   int T, int H) {
    const int n   = blockIdx.x;
    const int tid = threadIdx.x;
    const int v   = tid & 63;   // float4 index within row (H/4 == 64)
    const int tg  = tid >> 6;   // wave id 0..3

    const f4* xr = reinterpret_cast<const f4*>(x + (size_t)n * T * H);
    f4 a0 = {0.f, 0.f, 0.f, 0.f}, a1 = a0, a2 = a0, a3 = a0;
    for (int t = tg; t < T; t += 16) {
        f4 d0 = __builtin_nontemporal_load(&xr[(t     ) * 64 + v]);
        f4 d1 = __builtin_nontemporal_load(&xr[(t +  4) * 64 + v]);
        f4 d2 = __builtin_nontemporal_load(&xr[(t +  8) * 64 + v]);
        f4 d3 = __builtin_nontemporal_load(&xr[(t + 12) * 64 + v]);
        a0 += d0; a1 += d1; a2 += d2; a3 += d3;
    }
    __shared__ f4 red[256];
    red[tid] = (a0 + a1) + (a2 + a3);
    __syncthreads();
    if (tid < 64) {
        f4 o = (red[tid] + red[tid + 64]) + (red[tid + 128] + red[tid + 192]);
        float s = 1.0f / (float)T;
        o *= s;
        reinterpret_cast<f4*>(xagg + (size_t)n * H)[v] = o;
    }
}

// ---------------- Kernel 2: e = normalize(x_agg @ W^T) ----------------
__global__ __launch_bounds__(128) void proj_norm_kernel(const float* __restrict__ xagg,
                                                        const float* __restrict__ W,
                                                        float* __restrict__ e,
                                                        int H /*256*/) {
    const int n = blockIdx.x;
    const int j = threadIdx.x;  // 0..127

    __shared__ float xs[256];
    xs[j]       = xagg[(size_t)n * H + j];
    xs[j + 128] = xagg[(size_t)n * H + j + 128];
    __syncthreads();

    const float* Wr = W + (size_t)j * H;
    float acc = 0.f;
    #pragma unroll 8
    for (int c = 0; c < 256; ++c) acc = fmaf(Wr[c], xs[c], acc);

    float s = acc * acc;
    #pragma unroll
    for (int off = 32; off; off >>= 1) s += __shfl_xor(s, off);
    __shared__ float nrm[2];
    if ((j & 63) == 0) nrm[j >> 6] = s;
    __syncthreads();
    float tot = nrm[0] + nrm[1];
    float inv = 1.0f / fmaxf(sqrtf(tot), 1e-12f);
    e[(size_t)n * 128 + j] = acc * inv;
}

// ---------------- Kernel 3: sim rows + top-11 extraction + dyn scatter --------
// ROWS=4 rows per block, 256 threads. Phase A: j outer, c4 inner — each
// thread streams its e-row sequentially (full cache-line reuse); eL reads
// are wave-uniform broadcasts. (c4-outer register tile thrashed L1; do not
// reintroduce.) Phase B: wave w extracts top-11 (value desc, index asc),
// drops rank 0 (self).
#define TK_ROWS 4
__global__ __launch_bounds__(256) void simtopk_kernel(const float* __restrict__ e,
                                                      const float* __restrict__ mix,
                                                      float* __restrict__ out,
                                                      int N /*2048*/, int E /*65536*/) {
    __shared__ float eL[TK_ROWS][128];
    __shared__ float simL[TK_ROWS][2048];

    const int i0  = blockIdx.x * TK_ROWS;
    const int tid = threadIdx.x;
    const int M   = E + N * 10;  // 86016

    {
        int r = tid >> 6;
        int c = tid & 63;
        const float* er = e + (size_t)(i0 + r) * 128;
        eL[r][c]      = er[c];
        eL[r][c + 64] = er[c + 64];
    }
    __syncthreads();

    // Phase A: sims for all j, 4 rows at once (j outer, c4 inner)
    for (int j = tid; j < N; j += 256) {
        const f4* ej = reinterpret_cast<const f4*>(e + (size_t)j * 128);
        float acc[TK_ROWS] = {0.f, 0.f, 0.f, 0.f};
        #pragma unroll 4
        for (int c4 = 0; c4 < 32; ++c4) {
            f4 vv = ej[c4];
            #pragma unroll
            for (int r = 0; r < TK_ROWS; ++r) {
                const float* el = &eL[r][c4 * 4];
                acc[r] = fmaf(vv.x, el[0], acc[r]);
                acc[r] = fmaf(vv.y, el[1], acc[r]);
                acc[r] = fmaf(vv.z, el[2], acc[r]);
                acc[r] = fmaf(vv.w, el[3], acc[r]);
            }
        }
        #pragma unroll
        for (int r = 0; r < TK_ROWS; ++r) simL[r][j] = acc[r];
    }
    __syncthreads();

    // Phase B: wave w owns row i0+w
    const int w    = tid >> 6;
    const int lane = tid & 63;
    const int i    = i0 + w;
    const float alpha = 1.0f / (1.0f + expf(-mix[0]));

    float keepv = 0.f;
    int   keepi = 0;
    for (int round = 0; round < 11; ++round) {
        float bv = -3.0f;
        int   bi = N;  // larger than any real index so ties prefer real
        for (int t = 0; t < 32; ++t) {
            int j = t * 64 + lane;
            float v = simL[w][j];
            if (v > bv || (v == bv && j < bi)) { bv = v; bi = j; }
        }
        #pragma unroll
        for (int off = 32; off; off >>= 1) {
            float ov = __shfl_xor(bv, off);
            int   oi = __shfl_xor(bi, off);
            if (ov > bv || (ov == bv && oi < bi)) { bv = ov; bi = oi; }
        }
        if ((bi & 63) == lane && bi < N) simL[w][bi] = -3.0f;
        if (lane == round) { keepv = bv; keepi = bi; }
    }
    if (lane >= 1 && lane <= 10) {
        int kk  = lane - 1;
        int pos = i * 10 + kk;
        out[(size_t)E + pos]         = (float)i;      // row0: src
        out[(size_t)M + E + pos]     = (float)keepi;  // row1: dst
        out[2 * (size_t)M + E + pos] = keepv * alpha; // attr
    }
}

// ---------------- Kernel 4: fixed edges copy/scale ----------------
__global__ __launch_bounds__(256) void fixed_kernel(const int* __restrict__ ei,
                                                    const float* __restrict__ ea,
                                                    const float* __restrict__ mix,
                                                    float* __restrict__ out,
                                                    int E, int M) {
    const int idx = blockIdx.x * blockDim.x + threadIdx.x;
    if (idx < E) {
        float alpha = 1.0f / (1.0f + expf(-mix[0]));
        out[idx]                 = (float)ei[idx];            // row0 fixed src
        out[(size_t)M + idx]     = (float)ei[E + idx];        // row1 fixed dst
        out[2 * (size_t)M + idx] = ea[idx] * (1.0f - alpha);  // fixed attr
    }
}

extern "C" void kernel_launch(void* const* d_in, const int* in_sizes, int n_in,
                              void* d_out, int out_size, void* d_ws, size_t ws_size,
                              hipStream_t stream) {
    const float* x   = (const float*)d_in[0];
    const int*   ei  = (const int*)d_in[1];
    const float* ea  = (const float*)d_in[2];
    const float* W   = (const float*)d_in[3];
    const float* mix = (const float*)d_in[4];

    const int H  = 256;
    const int E  = in_sizes[2];                       // 65536
    const int M  = out_size / 3;                      // 86016
    const int N  = (M - E) / 10;                      // 2048
    const int T  = (int)((size_t)in_sizes[0] / ((size_t)N * H)); // 512

    float* xagg = (float*)d_ws;                       // N*H floats (2 MB)
    float* e    = xagg + (size_t)N * H;               // N*128 floats (1 MB)
    float* out  = (float*)d_out;

    mean_kernel<<<N, 256, 0, stream>>>(x, xagg, T, H);
    proj_norm_kernel<<<N, 128, 0, stream>>>(xagg, W, e, H);
    simtopk_kernel<<<N / TK_ROWS, 256, 0, stream>>>(e, mix, out, N, E);
    fixed_kernel<<<(E + 255) / 256, 256, 0, stream>>>(ei, ea, mix, out, E, M);
}